// Round 6
// baseline (89.169 us; speedup 1.0000x reference)
//
#include <hip/hip_runtime.h>

#define N 8192
#define D 64
#define GRAM_BLOCKS 128
#define APPLY_BLOCKS 512

// Kernel 1: G = S^T S (64x64) and t = colsum(S), via register-tiled outer
// products. Thread (ty,tx) in a 16x16 grid owns the 4x4 block
// G[4ty..4ty+3][4tx..4tx+3]. Two float4 loads per row, no LDS, no barriers.
__global__ __launch_bounds__(256) void gram_kernel(const float* __restrict__ S,
                                                   float* __restrict__ G,
                                                   float* __restrict__ t) {
    const int tid = threadIdx.x;
    const int ty = tid >> 4;                 // 0..15
    const int tx = tid & 15;                 // 0..15

    float acc[4][4];
#pragma unroll
    for (int i = 0; i < 4; ++i)
#pragma unroll
        for (int j = 0; j < 4; ++j) acc[i][j] = 0.f;
    float tac[4] = {0.f, 0.f, 0.f, 0.f};

    const int rpb = N / GRAM_BLOCKS;         // 64 rows per block
    const int r0 = blockIdx.x * rpb;
    const float* Sa = S + (size_t)r0 * D + 4 * ty;
    const float* Sb = S + (size_t)r0 * D + 4 * tx;

#pragma unroll 4
    for (int r = 0; r < rpb; ++r) {
        const float4 a = *(const float4*)(Sa + (size_t)r * D);
        const float4 b = *(const float4*)(Sb + (size_t)r * D);
        const float av[4] = {a.x, a.y, a.z, a.w};
        const float bv[4] = {b.x, b.y, b.z, b.w};
#pragma unroll
        for (int i = 0; i < 4; ++i)
#pragma unroll
            for (int j = 0; j < 4; ++j) acc[i][j] += av[i] * bv[j];
        if (ty == 0) {
#pragma unroll
            for (int j = 0; j < 4; ++j) tac[j] += bv[j];
        }
    }

#pragma unroll
    for (int i = 0; i < 4; ++i)
#pragma unroll
        for (int j = 0; j < 4; ++j)
            atomicAdd(&G[(4 * ty + i) * D + 4 * tx + j], acc[i][j]);
    if (ty == 0) {
#pragma unroll
        for (int j = 0; j < 4; ++j) atomicAdd(&t[4 * tx + j], tac[j]);
    }
}

// Kernel 2: out[i,:] = (s_i @ G) / (s_i . t). One wave per 4 rows, processed
// as 2 interleaved pairs (2 indep FMA chains sharing the Gs LDS reads);
// denominator via 6-step butterfly reduce instead of a 64-FMA chain.
__global__ __launch_bounds__(256) void apply_kernel(const float* __restrict__ S,
                                                    const float* __restrict__ G,
                                                    const float* __restrict__ t,
                                                    float* __restrict__ out) {
    __shared__ float Gs[D * D];
    __shared__ float ts[D];
    const int tid = threadIdx.x;
#pragma unroll
    for (int i = tid; i < (D * D) / 4; i += 256)
        ((float4*)Gs)[i] = ((const float4*)G)[i];
    if (tid < D) ts[tid] = t[tid];
    __syncthreads();

    const int lane = tid & 63;
    const int wid = tid >> 6;
    const float tl = ts[lane];
    const int i0 = (blockIdx.x * 4 + wid) * 4;        // 4 rows per wave

#pragma unroll
    for (int p = 0; p < 2; ++p) {
        const int ia = i0 + 2 * p;
        const int ib = ia + 1;
        const float va = S[(size_t)ia * D + lane];
        const float vb = S[(size_t)ib * D + lane];

        // denominators: rs = dot(v, t), butterfly-reduced, result in all lanes
        float pa = va * tl, pb = vb * tl;
#pragma unroll
        for (int s = 1; s < 64; s <<= 1) {
            pa += __shfl_xor(pa, s, 64);
            pb += __shfl_xor(pb, s, 64);
        }

        float aa = 0.f, ab = 0.f;
#pragma unroll
        for (int k = 0; k < D; ++k) {
            const float g = Gs[k * D + lane];         // stride-1: conflict-free
            aa += __shfl(va, k, 64) * g;              // constant lane -> readlane
            ab += __shfl(vb, k, 64) * g;
        }
        out[(size_t)ia * D + lane] = aa / pa;
        out[(size_t)ib * D + lane] = ab / pb;
    }
}

extern "C" void kernel_launch(void* const* d_in, const int* in_sizes, int n_in,
                              void* d_out, int out_size, void* d_ws, size_t ws_size,
                              hipStream_t stream) {
    const float* S = (const float*)d_in[0];
    float* out = (float*)d_out;
    float* G = (float*)d_ws;
    float* t = G + D * D;

    hipMemsetAsync(d_ws, 0, (D * D + D) * sizeof(float), stream);
    gram_kernel<<<GRAM_BLOCKS, 256, 0, stream>>>(S, G, t);
    apply_kernel<<<APPLY_BLOCKS, 256, 0, stream>>>(S, G, t, out);
}